// Round 12
// baseline (4708.590 us; speedup 1.0000x reference)
//
#include <hip/hip_runtime.h>
#include <stdint.h>

#define Hh   51
#define Bsz  1024
#define Tin  512
#define Ttot 576      // Tin + future(64)
#define NBB  2        // batches per block -> grid 512 = 2 blocks/CU (co-residency)
#define NW   7        // waves per block; each wave owns 2 M-tiles (14 >= 13)
#define BLK  (NW*64)  // 448
#define BST  136      // per-batch k-stride (uint16) = 68 dwords (no 4-way alias)

typedef __attribute__((ext_vector_type(8))) short short8;   // 8 x bf16 frag
typedef __attribute__((ext_vector_type(4))) float f32x4;    // C/D frag

__device__ __forceinline__ float fsig(float x){ return 1.f/(1.f+__expf(-x)); }
__device__ __forceinline__ float ftanh(float x){ return 2.f*fsig(2.f*x)-1.f; }
__device__ __forceinline__ uint16_t f2bf(float f){
    union{float f;uint32_t u;} v; v.f=f;
    return (uint16_t)((v.u + 0x7fffu + ((v.u>>16)&1u)) >> 16);   // RNE
}
__device__ __forceinline__ float bf2f(uint16_t h){
    union{uint32_t u;float f;} v; v.u=(uint32_t)h<<16; return v.f;
}
#define MFMA __builtin_amdgcn_mfma_f32_16x16x32_bf16

// R10 structure (best measured: in-register cells, 2 barriers, parity dbuf)
// with NBB=16 -> 2: grid 512 puts TWO independent barrier domains on every CU,
// so one block's chain stalls (ds_read latency, MFMA acc chains, exp chains,
// barrier skew) are hidden by the other block's issue. R9-R11 showed the
// machine >80% idle inside one domain; co-residency is the untested lever.
// MFMA N=16 is 8x underused by real batches - irrelevant at 5% MfmaUtil.
// Garbage columns (nn>=2) compute bounded garbage, never read.
__global__ __launch_bounds__(BLK, 4)
void lstm_mfma5(const float* __restrict__ inp,    // [B, Tin]
                const float* __restrict__ Wih1,   // [204, 1]
                const float* __restrict__ Whh1,   // [204, 51]
                const float* __restrict__ bih1,   // [204]
                const float* __restrict__ bhh1,   // [204]
                const float* __restrict__ Wih2,   // [204, 51]
                const float* __restrict__ Whh2,   // [204, 51]
                const float* __restrict__ bih2,   // [204]
                const float* __restrict__ bhh2,   // [204]
                const float* __restrict__ Wl,     // [1, 51]
                const float* __restrict__ blp,    // [1]
                float* __restrict__ outp)         // [B, Ttot]
{
    const int tid = threadIdx.x;
    const int wv  = tid >> 6, ln = tid & 63;
    const int quad = ln >> 4, nn = ln & 15;
    const int b0  = blockIdx.x * NBB;
    const int bnn = (nn < NBB) ? nn : (NBB - 1);   // clamped batch for gathers

    __shared__ __align__(16) uint16_t Bhi[2][16*BST];
    __shared__ __align__(16) uint16_t Blo[2][16*BST];
    __shared__ float wsum[NW*17];         // per-wave output partials [wv][nn]

    for (int k = tid; k < 16*BST; k += BLK) {
        Bhi[0][k] = 0; Bhi[1][k] = 0; Blo[0][k] = 0; Blo[1][k] = 0;
    }
    if (tid < NW*17) wsum[tid] = 0.f;

    // ---- A fragments for 2 tiles, weights split bf16 hi/lo (3-product) ----
    short8 a1hi[2][2], a1lo[2][2], a2hi[2][4], a2lo[2][4];
    f32x4 bias1[2], bias2[2], wih1v[2];
    float wlu[2]; int ut[2]; bool uvt[2];
#pragma unroll
    for (int tl = 0; tl < 2; ++tl) {
        const int lr = 16*(wv + 7*tl) + nn;       // this lane's logical A row
        const int ua = lr >> 2, ga = lr & 3;      // unit / gate of that row
        const bool av = (ua < Hh);
        const int pr = av ? (ga*Hh + ua) : 0;     // physical PyTorch row
#pragma unroll
        for (int s = 0; s < 2; ++s)
#pragma unroll
            for (int j = 0; j < 8; ++j) {
                int k = 32*s + quad*8 + j;
                float w = (av && k < Hh) ? Whh1[pr*Hh + k] : 0.f;
                uint16_t hh = f2bf(w);
                a1hi[tl][s][j] = (short)hh;
                a1lo[tl][s][j] = (short)f2bf(w - bf2f(hh));
            }
#pragma unroll
        for (int s = 0; s < 4; ++s)
#pragma unroll
            for (int j = 0; j < 8; ++j) {
                int k = 32*s + quad*8 + j;
                float w = 0.f;
                if (av) {
                    if (k < Hh)                    w = Wih2[pr*Hh + k];
                    else if (k >= 64 && k < 64+Hh) w = Whh2[pr*Hh + (k-64)];
                }
                uint16_t hh = f2bf(w);
                a2hi[tl][s][j] = (short)hh;
                a2lo[tl][s][j] = (short)f2bf(w - bf2f(hh));
            }
        const int u = 4*(wv + 7*tl) + quad;       // unit this lane's cell owns
        ut[tl] = u; uvt[tl] = (u < Hh);
#pragma unroll
        for (int i = 0; i < 4; ++i) {
            int pri = uvt[tl] ? (i*Hh + u) : 0;
            bias1[tl][i] = uvt[tl] ? (bih1[pri] + bhh1[pri]) : 0.f;
            bias2[tl][i] = uvt[tl] ? (bih2[pri] + bhh2[pri]) : 0.f;
            wih1v[tl][i] = uvt[tl] ? Wih1[pri] : 0.f;
        }
        wlu[tl] = uvt[tl] ? Wl[ut[tl]] : 0.f;
    }
    const float blv = blp[0];
    float c1[2] = {0.f, 0.f}, c2[2] = {0.f, 0.f};
    float xreg = inp[(size_t)(b0 + bnn)*Tin];     // x for t=0 (clamped lane)

    __syncthreads();

    for (int t = 0; t < Ttot; ++t) {
        const int p0 = t & 1, p1 = p0 ^ 1;

        // ---- front: previous step's output (wave NW-1 stores; all waves
        // need it as x in the future phase) ----
        float x = xreg;
        if ((t >= Tin || wv == NW-1) && t > 0) {
            float osum = blv;
#pragma unroll
            for (int w = 0; w < NW; ++w) osum += wsum[w*17 + nn];
            if (wv == NW-1 && ln < NBB)
                outp[(size_t)(b0 + ln)*Ttot + (t-1)] = osum;
            if (t >= Tin) x = osum;
        }
        float xnext = 0.f;
        if (t + 1 < Tin) xnext = inp[(size_t)(b0 + bnn)*Tin + t + 1];

        // ================= L1: GEMM + in-register cells =================
        {
            const uint16_t* rb = &Bhi[p1][nn*BST + quad*8];
            const uint16_t* rl = &Blo[p1][nn*BST + quad*8];
            short8 h0 = *(const short8*)(rb),      h1f = *(const short8*)(rb + 32);
            short8 l0 = *(const short8*)(rl),      l1f = *(const short8*)(rl + 32);
            f32x4 aA[2], aB[2];
#pragma unroll
            for (int tl = 0; tl < 2; ++tl) {
#pragma unroll
                for (int i = 0; i < 4; ++i)
                    aA[tl][i] = __builtin_fmaf(wih1v[tl][i], x, bias1[tl][i]);
                aB[tl] = (f32x4){0.f,0.f,0.f,0.f};
            }
            aA[0] = MFMA(a1hi[0][0], h0, aA[0], 0,0,0);
            aB[0] = MFMA(a1hi[0][1], h1f, aB[0], 0,0,0);
            aA[1] = MFMA(a1hi[1][0], h0, aA[1], 0,0,0);
            aB[1] = MFMA(a1hi[1][1], h1f, aB[1], 0,0,0);
            aA[0] = MFMA(a1lo[0][0], h0, aA[0], 0,0,0);
            aB[0] = MFMA(a1lo[0][1], h1f, aB[0], 0,0,0);
            aA[1] = MFMA(a1lo[1][0], h0, aA[1], 0,0,0);
            aB[1] = MFMA(a1lo[1][1], h1f, aB[1], 0,0,0);
            aA[0] = MFMA(a1hi[0][0], l0, aA[0], 0,0,0);
            aB[0] = MFMA(a1hi[0][1], l1f, aB[0], 0,0,0);
            aA[1] = MFMA(a1hi[1][0], l0, aA[1], 0,0,0);
            aB[1] = MFMA(a1hi[1][1], l1f, aB[1], 0,0,0);
#pragma unroll
            for (int tl = 0; tl < 2; ++tl) {
                float vi = aA[tl][0]+aB[tl][0], vf = aA[tl][1]+aB[tl][1];
                float vg = aA[tl][2]+aB[tl][2], vo = aA[tl][3]+aB[tl][3];
                c1[tl] = __builtin_fmaf(fsig(vf), c1[tl], fsig(vi)*ftanh(vg));
                float h1n = fsig(vo) * ftanh(c1[tl]);
                if (uvt[tl]) {
                    uint16_t hh = f2bf(h1n);
                    int ad = nn*BST + ut[tl];
                    Bhi[p0][ad] = hh; Blo[p0][ad] = f2bf(h1n - bf2f(hh));
                }
            }
        }
        __syncthreads();                                   // bar 1

        // ============ L2: GEMM over [h1_t | 0 | h2_{t-1}] + cells ============
        float h2v[2];
        {
            const uint16_t* rb0 = &Bhi[p0][nn*BST + quad*8];   // h1_t
            const uint16_t* rl0 = &Blo[p0][nn*BST + quad*8];
            const uint16_t* rb1 = &Bhi[p1][nn*BST + quad*8];   // h2_{t-1}
            const uint16_t* rl1 = &Blo[p1][nn*BST + quad*8];
            short8 s0h = *(const short8*)(rb0),      s1h = *(const short8*)(rb0 + 32);
            short8 s0l = *(const short8*)(rl0),      s1l = *(const short8*)(rl0 + 32);
            short8 s2h = *(const short8*)(rb1 + 64), s3h = *(const short8*)(rb1 + 96);
            short8 s2l = *(const short8*)(rl1 + 64), s3l = *(const short8*)(rl1 + 96);
            f32x4 aA[2], aB[2];
#pragma unroll
            for (int tl = 0; tl < 2; ++tl) {
                aA[tl] = bias2[tl];
                aB[tl] = (f32x4){0.f,0.f,0.f,0.f};
            }
#pragma unroll
            for (int tl = 0; tl < 2; ++tl) {
                aA[tl] = MFMA(a2hi[tl][0], s0h, aA[tl], 0,0,0);
                aB[tl] = MFMA(a2hi[tl][1], s1h, aB[tl], 0,0,0);
                aA[tl] = MFMA(a2lo[tl][0], s0h, aA[tl], 0,0,0);
                aB[tl] = MFMA(a2lo[tl][1], s1h, aB[tl], 0,0,0);
                aA[tl] = MFMA(a2hi[tl][0], s0l, aA[tl], 0,0,0);
                aB[tl] = MFMA(a2hi[tl][1], s1l, aB[tl], 0,0,0);
                aA[tl] = MFMA(a2hi[tl][2], s2h, aA[tl], 0,0,0);
                aB[tl] = MFMA(a2hi[tl][3], s3h, aB[tl], 0,0,0);
                aA[tl] = MFMA(a2lo[tl][2], s2h, aA[tl], 0,0,0);
                aB[tl] = MFMA(a2lo[tl][3], s3h, aB[tl], 0,0,0);
                aA[tl] = MFMA(a2hi[tl][2], s2l, aA[tl], 0,0,0);
                aB[tl] = MFMA(a2hi[tl][3], s3l, aB[tl], 0,0,0);
            }
#pragma unroll
            for (int tl = 0; tl < 2; ++tl) {
                float vi = aA[tl][0]+aB[tl][0], vf = aA[tl][1]+aB[tl][1];
                float vg = aA[tl][2]+aB[tl][2], vo = aA[tl][3]+aB[tl][3];
                c2[tl] = __builtin_fmaf(fsig(vf), c2[tl], fsig(vi)*ftanh(vg));
                h2v[tl] = fsig(vo) * ftanh(c2[tl]);
                if (uvt[tl]) {
                    uint16_t hh = f2bf(h2v[tl]);
                    int ad = nn*BST + 64 + ut[tl];
                    Bhi[p0][ad] = hh; Blo[p0][ad] = f2bf(h2v[tl] - bf2f(hh));
                }
            }
            // output partials over this wave's 8 units (2 tiles x 4 quads)
            float part = __builtin_fmaf(wlu[0], h2v[0], wlu[1]*h2v[1]);
            part += __shfl_xor(part, 16, 64);
            part += __shfl_xor(part, 32, 64);
            if (quad == 0) wsum[wv*17 + nn] = part;
        }
        __syncthreads();                                   // bar 2
        xreg = xnext;
    }

    // final output (t = Ttot-1)
    if (wv == NW-1) {
        float osum = blv;
#pragma unroll
        for (int w = 0; w < NW; ++w) osum += wsum[w*17 + nn];
        if (ln < NBB) outp[(size_t)(b0 + ln)*Ttot + (Ttot-1)] = osum;
    }
}

extern "C" void kernel_launch(void* const* d_in, const int* in_sizes, int n_in,
                              void* d_out, int out_size, void* d_ws, size_t ws_size,
                              hipStream_t stream) {
    (void)in_sizes; (void)n_in; (void)out_size; (void)d_ws; (void)ws_size;
    lstm_mfma5<<<dim3(Bsz / NBB), dim3(BLK), 0, stream>>>(
        (const float*)d_in[0], (const float*)d_in[1],
        (const float*)d_in[2], (const float*)d_in[3],
        (const float*)d_in[4], (const float*)d_in[5],
        (const float*)d_in[6], (const float*)d_in[7],
        (const float*)d_in[8], (const float*)d_in[9],
        (const float*)d_in[10], (float*)d_out);
}

// Round 13
// 2477.870 us; speedup vs baseline: 1.9003x; 1.9003x over previous
//
#include <hip/hip_runtime.h>
#include <stdint.h>

#define Hh   51
#define Bsz  1024
#define Tin  512
#define Ttot 576      // Tin + future(64)
#define NBB  2        // batches per block -> grid 512 = 2 blocks/CU (co-residency)
#define NW   7        // waves per block; each wave owns 2 M-tiles (14 >= 13)
#define BLK  (NW*64)  // 448
#define BST  136      // per-batch k-stride (uint16) = 68 dwords (no 4-way alias)

typedef __attribute__((ext_vector_type(8))) short short8;   // 8 x bf16 frag
typedef __attribute__((ext_vector_type(4))) float f32x4;    // C/D frag

__device__ __forceinline__ float fsig(float x){ return 1.f/(1.f+__expf(-x)); }
__device__ __forceinline__ float ftanh(float x){ return 2.f*fsig(2.f*x)-1.f; }
__device__ __forceinline__ uint16_t f2bf(float f){
    union{float f;uint32_t u;} v; v.f=f;
    return (uint16_t)((v.u + 0x7fffu + ((v.u>>16)&1u)) >> 16);   // RNE
}
__device__ __forceinline__ float bf2f(uint16_t h){
    union{uint32_t u;float f;} v; v.u=(uint32_t)h<<16; return v.f;
}
#define MFMA __builtin_amdgcn_mfma_f32_16x16x32_bf16

// R12 retry WITHOUT the confound: launch_bounds back to (448, 2) = the
// R10-proven 256-reg budget (VGPR 112, zero spill). R12's (448,4) cut the
// budget to 128 and spilled all 24 A-fragments to scratch (FETCH 16 GB,
// WRITE 107 MB) - the co-residency experiment never actually ran.
// NBB=2 -> grid 512 = 2 independent barrier domains per CU: one block's
// chain stalls (ds_read, MFMA chains, exp, barrier skew) hide under the
// other block's issue. Garbage B-columns (nn>=2) are bounded, never read.
__global__ __launch_bounds__(BLK, 2)
void lstm_mfma6(const float* __restrict__ inp,    // [B, Tin]
                const float* __restrict__ Wih1,   // [204, 1]
                const float* __restrict__ Whh1,   // [204, 51]
                const float* __restrict__ bih1,   // [204]
                const float* __restrict__ bhh1,   // [204]
                const float* __restrict__ Wih2,   // [204, 51]
                const float* __restrict__ Whh2,   // [204, 51]
                const float* __restrict__ bih2,   // [204]
                const float* __restrict__ bhh2,   // [204]
                const float* __restrict__ Wl,     // [1, 51]
                const float* __restrict__ blp,    // [1]
                float* __restrict__ outp)         // [B, Ttot]
{
    const int tid = threadIdx.x;
    const int wv  = tid >> 6, ln = tid & 63;
    const int quad = ln >> 4, nn = ln & 15;
    const int b0  = blockIdx.x * NBB;
    const int bnn = (nn < NBB) ? nn : (NBB - 1);   // clamped batch for gathers

    __shared__ __align__(16) uint16_t Bhi[2][16*BST];
    __shared__ __align__(16) uint16_t Blo[2][16*BST];
    __shared__ float wsum[NW*17];         // per-wave output partials [wv][nn]

    for (int k = tid; k < 16*BST; k += BLK) {
        Bhi[0][k] = 0; Bhi[1][k] = 0; Blo[0][k] = 0; Blo[1][k] = 0;
    }
    if (tid < NW*17) wsum[tid] = 0.f;

    // ---- A fragments for 2 tiles, weights split bf16 hi/lo (3-product) ----
    short8 a1hi[2][2], a1lo[2][2], a2hi[2][4], a2lo[2][4];
    f32x4 bias1[2], bias2[2], wih1v[2];
    float wlu[2]; int ut[2]; bool uvt[2];
#pragma unroll
    for (int tl = 0; tl < 2; ++tl) {
        const int lr = 16*(wv + 7*tl) + nn;       // this lane's logical A row
        const int ua = lr >> 2, ga = lr & 3;      // unit / gate of that row
        const bool av = (ua < Hh);
        const int pr = av ? (ga*Hh + ua) : 0;     // physical PyTorch row
#pragma unroll
        for (int s = 0; s < 2; ++s)
#pragma unroll
            for (int j = 0; j < 8; ++j) {
                int k = 32*s + quad*8 + j;
                float w = (av && k < Hh) ? Whh1[pr*Hh + k] : 0.f;
                uint16_t hh = f2bf(w);
                a1hi[tl][s][j] = (short)hh;
                a1lo[tl][s][j] = (short)f2bf(w - bf2f(hh));
            }
#pragma unroll
        for (int s = 0; s < 4; ++s)
#pragma unroll
            for (int j = 0; j < 8; ++j) {
                int k = 32*s + quad*8 + j;
                float w = 0.f;
                if (av) {
                    if (k < Hh)                    w = Wih2[pr*Hh + k];
                    else if (k >= 64 && k < 64+Hh) w = Whh2[pr*Hh + (k-64)];
                }
                uint16_t hh = f2bf(w);
                a2hi[tl][s][j] = (short)hh;
                a2lo[tl][s][j] = (short)f2bf(w - bf2f(hh));
            }
        const int u = 4*(wv + 7*tl) + quad;       // unit this lane's cell owns
        ut[tl] = u; uvt[tl] = (u < Hh);
#pragma unroll
        for (int i = 0; i < 4; ++i) {
            int pri = uvt[tl] ? (i*Hh + u) : 0;
            bias1[tl][i] = uvt[tl] ? (bih1[pri] + bhh1[pri]) : 0.f;
            bias2[tl][i] = uvt[tl] ? (bih2[pri] + bhh2[pri]) : 0.f;
            wih1v[tl][i] = uvt[tl] ? Wih1[pri] : 0.f;
        }
        wlu[tl] = uvt[tl] ? Wl[ut[tl]] : 0.f;
    }
    const float blv = blp[0];
    float c1[2] = {0.f, 0.f}, c2[2] = {0.f, 0.f};
    float xreg = inp[(size_t)(b0 + bnn)*Tin];     // x for t=0 (clamped lane)

    __syncthreads();

    for (int t = 0; t < Ttot; ++t) {
        const int p0 = t & 1, p1 = p0 ^ 1;

        // ---- front: previous step's output (wave NW-1 stores; all waves
        // need it as x in the future phase) ----
        float x = xreg;
        if ((t >= Tin || wv == NW-1) && t > 0) {
            float osum = blv;
#pragma unroll
            for (int w = 0; w < NW; ++w) osum += wsum[w*17 + nn];
            if (wv == NW-1 && ln < NBB)
                outp[(size_t)(b0 + ln)*Ttot + (t-1)] = osum;
            if (t >= Tin) x = osum;
        }
        float xnext = 0.f;
        if (t + 1 < Tin) xnext = inp[(size_t)(b0 + bnn)*Tin + t + 1];

        // ================= L1: GEMM + in-register cells =================
        {
            const uint16_t* rb = &Bhi[p1][nn*BST + quad*8];
            const uint16_t* rl = &Blo[p1][nn*BST + quad*8];
            short8 h0 = *(const short8*)(rb),      h1f = *(const short8*)(rb + 32);
            short8 l0 = *(const short8*)(rl),      l1f = *(const short8*)(rl + 32);
            f32x4 aA[2], aB[2];
#pragma unroll
            for (int tl = 0; tl < 2; ++tl) {
#pragma unroll
                for (int i = 0; i < 4; ++i)
                    aA[tl][i] = __builtin_fmaf(wih1v[tl][i], x, bias1[tl][i]);
                aB[tl] = (f32x4){0.f,0.f,0.f,0.f};
            }
            aA[0] = MFMA(a1hi[0][0], h0, aA[0], 0,0,0);
            aB[0] = MFMA(a1hi[0][1], h1f, aB[0], 0,0,0);
            aA[1] = MFMA(a1hi[1][0], h0, aA[1], 0,0,0);
            aB[1] = MFMA(a1hi[1][1], h1f, aB[1], 0,0,0);
            aA[0] = MFMA(a1lo[0][0], h0, aA[0], 0,0,0);
            aB[0] = MFMA(a1lo[0][1], h1f, aB[0], 0,0,0);
            aA[1] = MFMA(a1lo[1][0], h0, aA[1], 0,0,0);
            aB[1] = MFMA(a1lo[1][1], h1f, aB[1], 0,0,0);
            aA[0] = MFMA(a1hi[0][0], l0, aA[0], 0,0,0);
            aB[0] = MFMA(a1hi[0][1], l1f, aB[0], 0,0,0);
            aA[1] = MFMA(a1hi[1][0], l0, aA[1], 0,0,0);
            aB[1] = MFMA(a1hi[1][1], l1f, aB[1], 0,0,0);
#pragma unroll
            for (int tl = 0; tl < 2; ++tl) {
                float vi = aA[tl][0]+aB[tl][0], vf = aA[tl][1]+aB[tl][1];
                float vg = aA[tl][2]+aB[tl][2], vo = aA[tl][3]+aB[tl][3];
                c1[tl] = __builtin_fmaf(fsig(vf), c1[tl], fsig(vi)*ftanh(vg));
                float h1n = fsig(vo) * ftanh(c1[tl]);
                if (uvt[tl]) {
                    uint16_t hh = f2bf(h1n);
                    int ad = nn*BST + ut[tl];
                    Bhi[p0][ad] = hh; Blo[p0][ad] = f2bf(h1n - bf2f(hh));
                }
            }
        }
        __syncthreads();                                   // bar 1

        // ============ L2: GEMM over [h1_t | 0 | h2_{t-1}] + cells ============
        float h2v[2];
        {
            const uint16_t* rb0 = &Bhi[p0][nn*BST + quad*8];   // h1_t
            const uint16_t* rl0 = &Blo[p0][nn*BST + quad*8];
            const uint16_t* rb1 = &Bhi[p1][nn*BST + quad*8];   // h2_{t-1}
            const uint16_t* rl1 = &Blo[p1][nn*BST + quad*8];
            short8 s0h = *(const short8*)(rb0),      s1h = *(const short8*)(rb0 + 32);
            short8 s0l = *(const short8*)(rl0),      s1l = *(const short8*)(rl0 + 32);
            short8 s2h = *(const short8*)(rb1 + 64), s3h = *(const short8*)(rb1 + 96);
            short8 s2l = *(const short8*)(rl1 + 64), s3l = *(const short8*)(rl1 + 96);
            f32x4 aA[2], aB[2];
#pragma unroll
            for (int tl = 0; tl < 2; ++tl) {
                aA[tl] = bias2[tl];
                aB[tl] = (f32x4){0.f,0.f,0.f,0.f};
            }
#pragma unroll
            for (int tl = 0; tl < 2; ++tl) {
                aA[tl] = MFMA(a2hi[tl][0], s0h, aA[tl], 0,0,0);
                aB[tl] = MFMA(a2hi[tl][1], s1h, aB[tl], 0,0,0);
                aA[tl] = MFMA(a2lo[tl][0], s0h, aA[tl], 0,0,0);
                aB[tl] = MFMA(a2lo[tl][1], s1h, aB[tl], 0,0,0);
                aA[tl] = MFMA(a2hi[tl][0], s0l, aA[tl], 0,0,0);
                aB[tl] = MFMA(a2hi[tl][1], s1l, aB[tl], 0,0,0);
                aA[tl] = MFMA(a2hi[tl][2], s2h, aA[tl], 0,0,0);
                aB[tl] = MFMA(a2hi[tl][3], s3h, aB[tl], 0,0,0);
                aA[tl] = MFMA(a2lo[tl][2], s2h, aA[tl], 0,0,0);
                aB[tl] = MFMA(a2lo[tl][3], s3h, aB[tl], 0,0,0);
                aA[tl] = MFMA(a2hi[tl][2], s2l, aA[tl], 0,0,0);
                aB[tl] = MFMA(a2hi[tl][3], s3l, aB[tl], 0,0,0);
            }
#pragma unroll
            for (int tl = 0; tl < 2; ++tl) {
                float vi = aA[tl][0]+aB[tl][0], vf = aA[tl][1]+aB[tl][1];
                float vg = aA[tl][2]+aB[tl][2], vo = aA[tl][3]+aB[tl][3];
                c2[tl] = __builtin_fmaf(fsig(vf), c2[tl], fsig(vi)*ftanh(vg));
                h2v[tl] = fsig(vo) * ftanh(c2[tl]);
                if (uvt[tl]) {
                    uint16_t hh = f2bf(h2v[tl]);
                    int ad = nn*BST + 64 + ut[tl];
                    Bhi[p0][ad] = hh; Blo[p0][ad] = f2bf(h2v[tl] - bf2f(hh));
                }
            }
            // output partials over this wave's 8 units (2 tiles x 4 quads)
            float part = __builtin_fmaf(wlu[0], h2v[0], wlu[1]*h2v[1]);
            part += __shfl_xor(part, 16, 64);
            part += __shfl_xor(part, 32, 64);
            if (quad == 0) wsum[wv*17 + nn] = part;
        }
        __syncthreads();                                   // bar 2
        xreg = xnext;
    }

    // final output (t = Ttot-1)
    if (wv == NW-1) {
        float osum = blv;
#pragma unroll
        for (int w = 0; w < NW; ++w) osum += wsum[w*17 + nn];
        if (ln < NBB) outp[(size_t)(b0 + ln)*Ttot + (Ttot-1)] = osum;
    }
}

extern "C" void kernel_launch(void* const* d_in, const int* in_sizes, int n_in,
                              void* d_out, int out_size, void* d_ws, size_t ws_size,
                              hipStream_t stream) {
    (void)in_sizes; (void)n_in; (void)out_size; (void)d_ws; (void)ws_size;
    lstm_mfma6<<<dim3(Bsz / NBB), dim3(BLK), 0, stream>>>(
        (const float*)d_in[0], (const float*)d_in[1],
        (const float*)d_in[2], (const float*)d_in[3],
        (const float*)d_in[4], (const float*)d_in[5],
        (const float*)d_in[6], (const float*)d_in[7],
        (const float*)d_in[8], (const float*)d_in[9],
        (const float*)d_in[10], (float*)d_out);
}

// Round 14
// 735.064 us; speedup vs baseline: 6.4057x; 3.3710x over previous
//
#include <hip/hip_runtime.h>
#include <stdint.h>

#define Hh   51
#define Bsz  1024
#define Tin  512
#define Ttot 576      // Tin + future(64)
#define NBB  16       // batches per block (R10-proven config, grid 64)
#define NW   7        // waves per block; each wave owns 2 M-tiles (14 >= 13)
#define BLK  (NW*64)  // 448
#define BST  136      // per-batch k-stride (uint16) = 68 dwords (no 4-way alias)

#define L2E   1.4426950408889634f    // log2(e)
#define TL2E  2.8853900817779268f    // 2*log2(e)

typedef __attribute__((ext_vector_type(8))) short short8;   // 8 x bf16 frag
typedef __attribute__((ext_vector_type(4))) float f32x4;    // C/D frag

__device__ __forceinline__ float rcpf(float x){ return __builtin_amdgcn_rcpf(x); }
__device__ __forceinline__ float exp2f_fast(float x){
#if __has_builtin(__builtin_amdgcn_exp2f)
    return __builtin_amdgcn_exp2f(x);
#else
    return exp2f(x);
#endif
}
// pre-acts arrive PRE-SCALED by log2e (i,f,o rows) / 2*log2e (g rows):
__device__ __forceinline__ float sig2(float vp){          // sigmoid(v), vp=v*log2e
    return rcpf(1.f + exp2f_fast(-vp));
}
__device__ __forceinline__ float tanh2(float vp){         // tanh(v), vp=v*2log2e
    return __builtin_fmaf(2.f, rcpf(1.f + exp2f_fast(-vp)), -1.f);
}
__device__ __forceinline__ uint16_t f2bf(float f){
    union{float f;uint32_t u;} v; v.f=f;
    return (uint16_t)((v.u + 0x7fffu + ((v.u>>16)&1u)) >> 16);   // RNE
}
__device__ __forceinline__ float bf2f(uint16_t h){
    union{uint32_t u;float f;} v; v.u=(uint32_t)h<<16; return v.f;
}
#define MFMA __builtin_amdgcn_mfma_f32_16x16x32_bf16

// R10 structure (64 blocks, 14 waves, in-register cells, 2 barriers) with the
// instruction stream cut down (R13 showed busy CUs are ~80% ISSUE-saturated:
// GPU-wide VALUBusy 15.3% x 4 idle-factor = 61% on busy CUs):
//  (1) rcpf instead of IEEE div in all 5 activations/cell,
//  (2) log2e folded into A-weights/biases -> exp2-native activations,
//  (3) 2-product emulation: w = hi+lo exact, h = single RNE bf16
//      (MFMAs 36->24/wave, LDS reads 12->6, lo-plane gone).
__global__ __launch_bounds__(BLK, 2)
void lstm_mfma7(const float* __restrict__ inp,    // [B, Tin]
                const float* __restrict__ Wih1,   // [204, 1]
                const float* __restrict__ Whh1,   // [204, 51]
                const float* __restrict__ bih1,   // [204]
                const float* __restrict__ bhh1,   // [204]
                const float* __restrict__ Wih2,   // [204, 51]
                const float* __restrict__ Whh2,   // [204, 51]
                const float* __restrict__ bih2,   // [204]
                const float* __restrict__ bhh2,   // [204]
                const float* __restrict__ Wl,     // [1, 51]
                const float* __restrict__ blp,    // [1]
                float* __restrict__ outp)         // [B, Ttot]
{
    const int tid = threadIdx.x;
    const int wv  = tid >> 6, ln = tid & 63;
    const int quad = ln >> 4, nn = ln & 15;
    const int b0  = blockIdx.x * NBB;

    __shared__ __align__(16) uint16_t Bh[2][NBB*BST];
    __shared__ float wsum[NW*17];         // per-wave output partials [wv][nn]

    for (int k = tid; k < NBB*BST; k += BLK) { Bh[0][k] = 0; Bh[1][k] = 0; }
    if (tid < NW*17) wsum[tid] = 0.f;

    // ---- A fragments for 2 tiles; weights pre-scaled by log2e (2log2e for
    // g-gate rows), then split bf16 hi/lo so hi+lo ~= scaled fp32 weight ----
    short8 a1hi[2][2], a1lo[2][2], a2hi[2][4], a2lo[2][4];
    f32x4 bias1[2], bias2[2], wih1v[2];
    float wlu[2]; int ut[2]; bool uvt[2];
#pragma unroll
    for (int tl = 0; tl < 2; ++tl) {
        const int lr = 16*(wv + 7*tl) + nn;       // this lane's logical A row
        const int ua = lr >> 2, ga = lr & 3;      // unit / gate of that row
        const bool av = (ua < Hh);
        const int pr = av ? (ga*Hh + ua) : 0;     // physical PyTorch row
        const float rs = (ga == 2) ? TL2E : L2E;  // row activation pre-scale
#pragma unroll
        for (int s = 0; s < 2; ++s)
#pragma unroll
            for (int j = 0; j < 8; ++j) {
                int k = 32*s + quad*8 + j;
                float w = (av && k < Hh) ? Whh1[pr*Hh + k]*rs : 0.f;
                uint16_t hh = f2bf(w);
                a1hi[tl][s][j] = (short)hh;
                a1lo[tl][s][j] = (short)f2bf(w - bf2f(hh));
            }
#pragma unroll
        for (int s = 0; s < 4; ++s)
#pragma unroll
            for (int j = 0; j < 8; ++j) {
                int k = 32*s + quad*8 + j;
                float w = 0.f;
                if (av) {
                    if (k < Hh)                    w = Wih2[pr*Hh + k]*rs;
                    else if (k >= 64 && k < 64+Hh) w = Whh2[pr*Hh + (k-64)]*rs;
                }
                uint16_t hh = f2bf(w);
                a2hi[tl][s][j] = (short)hh;
                a2lo[tl][s][j] = (short)f2bf(w - bf2f(hh));
            }
        const int u = 4*(wv + 7*tl) + quad;       // unit this lane's cell owns
        ut[tl] = u; uvt[tl] = (u < Hh);
#pragma unroll
        for (int i = 0; i < 4; ++i) {
            int pri = uvt[tl] ? (i*Hh + u) : 0;
            float gs = (i == 2) ? TL2E : L2E;
            bias1[tl][i] = uvt[tl] ? (bih1[pri] + bhh1[pri])*gs : 0.f;
            bias2[tl][i] = uvt[tl] ? (bih2[pri] + bhh2[pri])*gs : 0.f;
            wih1v[tl][i] = uvt[tl] ? Wih1[pri]*gs : 0.f;
        }
        wlu[tl] = uvt[tl] ? Wl[ut[tl]] : 0.f;     // output weights unscaled
    }
    const float blv = blp[0];
    float c1[2] = {0.f, 0.f}, c2[2] = {0.f, 0.f};
    float xreg = inp[(size_t)(b0 + nn)*Tin];      // x for t=0

    __syncthreads();

    for (int t = 0; t < Ttot; ++t) {
        const int p0 = t & 1, p1 = p0 ^ 1;

        // ---- front: previous step's output (wave NW-1 stores; all waves
        // need it as x in the future phase) ----
        float x = xreg;
        if ((t >= Tin || wv == NW-1) && t > 0) {
            float osum = blv;
#pragma unroll
            for (int w = 0; w < NW; ++w) osum += wsum[w*17 + nn];
            if (wv == NW-1 && ln < NBB)
                outp[(size_t)(b0 + ln)*Ttot + (t-1)] = osum;
            if (t >= Tin) x = osum;
        }
        float xnext = 0.f;
        if (t + 1 < Tin) xnext = inp[(size_t)(b0 + nn)*Tin + t + 1];

        // ================= L1: GEMM + in-register cells =================
        {
            const uint16_t* rb = &Bh[p1][nn*BST + quad*8];
            short8 h0 = *(const short8*)(rb), h1f = *(const short8*)(rb + 32);
            // prefetch L2's h2_{t-1} fragments (stable in buf p1)
            short8 s2h = *(const short8*)(rb + 64), s3h = *(const short8*)(rb + 96);
            f32x4 aA[2], aB[2];
#pragma unroll
            for (int tl = 0; tl < 2; ++tl) {
#pragma unroll
                for (int i = 0; i < 4; ++i)
                    aA[tl][i] = __builtin_fmaf(wih1v[tl][i], x, bias1[tl][i]);
                aB[tl] = (f32x4){0.f,0.f,0.f,0.f};
            }
            aA[0] = MFMA(a1hi[0][0], h0, aA[0], 0,0,0);
            aB[0] = MFMA(a1hi[0][1], h1f, aB[0], 0,0,0);
            aA[1] = MFMA(a1hi[1][0], h0, aA[1], 0,0,0);
            aB[1] = MFMA(a1hi[1][1], h1f, aB[1], 0,0,0);
            aA[0] = MFMA(a1lo[0][0], h0, aA[0], 0,0,0);
            aB[0] = MFMA(a1lo[0][1], h1f, aB[0], 0,0,0);
            aA[1] = MFMA(a1lo[1][0], h0, aA[1], 0,0,0);
            aB[1] = MFMA(a1lo[1][1], h1f, aB[1], 0,0,0);
#pragma unroll
            for (int tl = 0; tl < 2; ++tl) {
                float vi = aA[tl][0]+aB[tl][0], vf = aA[tl][1]+aB[tl][1];
                float vg = aA[tl][2]+aB[tl][2], vo = aA[tl][3]+aB[tl][3];
                c1[tl] = __builtin_fmaf(sig2(vf), c1[tl], sig2(vi)*tanh2(vg));
                float h1n = sig2(vo) * tanh2(c1[tl]*TL2E);
                if (uvt[tl]) Bh[p0][nn*BST + ut[tl]] = f2bf(h1n);
            }
            // stash L2 prefetch in regs across the barrier via recompute-free path
            // (kept live: s2h/s3h used below)
            __syncthreads();                               // bar 1

            // ========== L2: GEMM over [h1_t | 0 | h2_{t-1}] + cells ==========
            const uint16_t* rb0 = &Bh[p0][nn*BST + quad*8];    // h1_t
            short8 s0h = *(const short8*)(rb0), s1h = *(const short8*)(rb0 + 32);
            f32x4 bA[2], bB[2];
#pragma unroll
            for (int tl = 0; tl < 2; ++tl) {
                bA[tl] = bias2[tl];
                bB[tl] = (f32x4){0.f,0.f,0.f,0.f};
            }
#pragma unroll
            for (int tl = 0; tl < 2; ++tl) {
                bA[tl] = MFMA(a2hi[tl][0], s0h, bA[tl], 0,0,0);
                bB[tl] = MFMA(a2hi[tl][1], s1h, bB[tl], 0,0,0);
                bA[tl] = MFMA(a2lo[tl][0], s0h, bA[tl], 0,0,0);
                bB[tl] = MFMA(a2lo[tl][1], s1h, bB[tl], 0,0,0);
                bA[tl] = MFMA(a2hi[tl][2], s2h, bA[tl], 0,0,0);
                bB[tl] = MFMA(a2hi[tl][3], s3h, bB[tl], 0,0,0);
                bA[tl] = MFMA(a2lo[tl][2], s2h, bA[tl], 0,0,0);
                bB[tl] = MFMA(a2lo[tl][3], s3h, bB[tl], 0,0,0);
            }
            float h2v[2];
#pragma unroll
            for (int tl = 0; tl < 2; ++tl) {
                float vi = bA[tl][0]+bB[tl][0], vf = bA[tl][1]+bB[tl][1];
                float vg = bA[tl][2]+bB[tl][2], vo = bA[tl][3]+bB[tl][3];
                c2[tl] = __builtin_fmaf(sig2(vf), c2[tl], sig2(vi)*tanh2(vg));
                h2v[tl] = sig2(vo) * tanh2(c2[tl]*TL2E);
                if (uvt[tl]) Bh[p0][nn*BST + 64 + ut[tl]] = f2bf(h2v[tl]);
            }
            // output partials over this wave's 8 units (2 tiles x 4 quads)
            float part = __builtin_fmaf(wlu[0], h2v[0], wlu[1]*h2v[1]);
            part += __shfl_xor(part, 16, 64);
            part += __shfl_xor(part, 32, 64);
            if (quad == 0) wsum[wv*17 + nn] = part;
        }
        __syncthreads();                                   // bar 2
        xreg = xnext;
    }

    // final output (t = Ttot-1)
    if (wv == NW-1) {
        float osum = blv;
#pragma unroll
        for (int w = 0; w < NW; ++w) osum += wsum[w*17 + nn];
        if (ln < NBB) outp[(size_t)(b0 + ln)*Ttot + (Ttot-1)] = osum;
    }
}

extern "C" void kernel_launch(void* const* d_in, const int* in_sizes, int n_in,
                              void* d_out, int out_size, void* d_ws, size_t ws_size,
                              hipStream_t stream) {
    (void)in_sizes; (void)n_in; (void)out_size; (void)d_ws; (void)ws_size;
    lstm_mfma7<<<dim3(Bsz / NBB), dim3(BLK), 0, stream>>>(
        (const float*)d_in[0], (const float*)d_in[1],
        (const float*)d_in[2], (const float*)d_in[3],
        (const float*)d_in[4], (const float*)d_in[5],
        (const float*)d_in[6], (const float*)d_in[7],
        (const float*)d_in[8], (const float*)d_in[9],
        (const float*)d_in[10], (float*)d_out);
}

// Round 15
// 683.350 us; speedup vs baseline: 6.8905x; 1.0757x over previous
//
#include <hip/hip_runtime.h>
#include <stdint.h>

#define Hh   51
#define Bsz  1024
#define Tin  512
#define Ttot 576      // Tin + future(64)
#define NBB  16       // batches per block (grid 64)
#define NW   7        // waves per block; each wave owns 2 M-tiles (14 >= 13)
#define BLK  (NW*64)  // 448
#define BST  136      // per-batch k-stride (uint16) = 68 dwords (no 4-way alias)

#define L2E   1.4426950408889634f    // log2(e)
#define TL2E  2.8853900817779268f    // 2*log2(e)

typedef __attribute__((ext_vector_type(8))) short short8;   // 8 x bf16 frag
typedef __attribute__((ext_vector_type(4))) float f32x4;    // C/D frag

__device__ __forceinline__ float rcpf(float x){ return __builtin_amdgcn_rcpf(x); }
__device__ __forceinline__ float exp2f_fast(float x){
#if __has_builtin(__builtin_amdgcn_exp2f)
    return __builtin_amdgcn_exp2f(x);
#else
    return exp2f(x);
#endif
}
__device__ __forceinline__ float sig2(float vp){          // sigmoid(v), vp=v*log2e
    return rcpf(1.f + exp2f_fast(-vp));
}
__device__ __forceinline__ float tanh2(float vp){         // tanh(v), vp=v*2log2e
    return __builtin_fmaf(2.f, rcpf(1.f + exp2f_fast(-vp)), -1.f);
}
__device__ __forceinline__ uint16_t f2bf(float f){
    union{float f;uint32_t u;} v; v.f=f;
    return (uint16_t)((v.u + 0x7fffu + ((v.u>>16)&1u)) >> 16);   // RNE
}
__device__ __forceinline__ float bf2f(uint16_t h){
    union{uint32_t u;float f;} v; v.u=(uint32_t)h<<16; return v.f;
}
#define MFMA __builtin_amdgcn_mfma_f32_16x16x32_bf16

// PHASE-FUSED: L1(t+1) depends only on h1(t), x(t+1) - NOT on h2(t). So one
// phase computes L2(t) AND L1(t+1) from one LDS read session, one barrier
// per input step (512 of 576). Future steps (x(t+1)=out(t) needs the Wl
// reduction) get a second sub-phase. Numerics identical to R14 (2-product
// split-bf16 weights, bf16 h, exp2-folded activations, rcpf).
__global__ __launch_bounds__(BLK, 2)
void lstm_mfma8(const float* __restrict__ inp,    // [B, Tin]
                const float* __restrict__ Wih1,   // [204, 1]
                const float* __restrict__ Whh1,   // [204, 51]
                const float* __restrict__ bih1,   // [204]
                const float* __restrict__ bhh1,   // [204]
                const float* __restrict__ Wih2,   // [204, 51]
                const float* __restrict__ Whh2,   // [204, 51]
                const float* __restrict__ bih2,   // [204]
                const float* __restrict__ bhh2,   // [204]
                const float* __restrict__ Wl,     // [1, 51]
                const float* __restrict__ blp,    // [1]
                float* __restrict__ outp)         // [B, Ttot]
{
    const int tid = threadIdx.x;
    const int wv  = tid >> 6, ln = tid & 63;
    const int quad = ln >> 4, nn = ln & 15;
    const int b0  = blockIdx.x * NBB;

    __shared__ __align__(16) uint16_t Bh[2][NBB*BST];
    __shared__ float wsum[2][NW*17];      // parity-dbuf output partials

    for (int k = tid; k < NBB*BST; k += BLK) { Bh[0][k] = 0; Bh[1][k] = 0; }
    if (tid < NW*17) { wsum[0][tid] = 0.f; wsum[1][tid] = 0.f; }

    // ---- A fragments for 2 tiles; weights pre-scaled by log2e (2log2e for
    // g rows), split bf16 hi/lo (2-product emulation, h single bf16) ----
    short8 a1hi[2][2], a1lo[2][2], a2hi[2][4], a2lo[2][4];
    f32x4 bias1[2], bias2[2], wih1v[2];
    float wlu[2]; int ut[2]; bool uvt[2], tvt[2];
#pragma unroll
    for (int tl = 0; tl < 2; ++tl) {
        tvt[tl] = (wv + 7*tl) < 13;
        const int lr = 16*(wv + 7*tl) + nn;
        const int ua = lr >> 2, ga = lr & 3;
        const bool av = tvt[tl] && (ua < Hh);
        const int pr = av ? (ga*Hh + ua) : 0;
        const float rs = (ga == 2) ? TL2E : L2E;
#pragma unroll
        for (int s = 0; s < 2; ++s)
#pragma unroll
            for (int j = 0; j < 8; ++j) {
                int k = 32*s + quad*8 + j;
                float w = (av && k < Hh) ? Whh1[pr*Hh + k]*rs : 0.f;
                uint16_t hh = f2bf(w);
                a1hi[tl][s][j] = (short)hh;
                a1lo[tl][s][j] = (short)f2bf(w - bf2f(hh));
            }
#pragma unroll
        for (int s = 0; s < 4; ++s)
#pragma unroll
            for (int j = 0; j < 8; ++j) {
                int k = 32*s + quad*8 + j;
                float w = 0.f;
                if (av) {
                    if (k < Hh)                    w = Wih2[pr*Hh + k]*rs;
                    else if (k >= 64 && k < 64+Hh) w = Whh2[pr*Hh + (k-64)]*rs;
                }
                uint16_t hh = f2bf(w);
                a2hi[tl][s][j] = (short)hh;
                a2lo[tl][s][j] = (short)f2bf(w - bf2f(hh));
            }
        const int u = 4*(wv + 7*tl) + quad;
        ut[tl] = u; uvt[tl] = tvt[tl] && (u < Hh);
#pragma unroll
        for (int i = 0; i < 4; ++i) {
            int pri = uvt[tl] ? (i*Hh + u) : 0;
            float gs = (i == 2) ? TL2E : L2E;
            bias1[tl][i] = uvt[tl] ? (bih1[pri] + bhh1[pri])*gs : 0.f;
            bias2[tl][i] = uvt[tl] ? (bih2[pri] + bhh2[pri])*gs : 0.f;
            wih1v[tl][i] = uvt[tl] ? Wih1[pri]*gs : 0.f;
        }
        wlu[tl] = uvt[tl] ? Wl[ut[tl]] : 0.f;
    }
    const float blv = blp[0];
    float c1[2] = {0.f, 0.f}, c2[2] = {0.f, 0.f};

    // ---- prologue: h1(0) = cell(c1=0, b1 + x0*wih1) -> Bh[0] ----
    {
        float x0 = inp[(size_t)(b0 + nn)*Tin];
#pragma unroll
        for (int tl = 0; tl < 2; ++tl) {
            float vi = __builtin_fmaf(wih1v[tl][0], x0, bias1[tl][0]);
            float vf = __builtin_fmaf(wih1v[tl][1], x0, bias1[tl][1]);
            float vg = __builtin_fmaf(wih1v[tl][2], x0, bias1[tl][2]);
            float vo = __builtin_fmaf(wih1v[tl][3], x0, bias1[tl][3]);
            (void)vf;
            c1[tl] = sig2(vi) * tanh2(vg);
            float h1n = sig2(vo) * tanh2(c1[tl]*TL2E);
            if (uvt[tl]) Bh[0][nn*BST + ut[tl]] = f2bf(h1n);
        }
    }
    float xreg = (Tin > 1) ? inp[(size_t)(b0 + nn)*Tin + 1] : 0.f;  // x(1)
    __syncthreads();

    for (int t = 0; t < Ttot; ++t) {
        const int cur = t & 1, nxt = cur ^ 1;
        const bool inmode = (t + 1 < Tin);

        // out(t-1) write (wave NW-1, reads previous phase's wsum[nxt])
        if (wv == NW-1 && t > 0) {
            float osum = blv;
#pragma unroll
            for (int w = 0; w < NW; ++w) osum += wsum[nxt][w*17 + nn];
            if (ln < NBB) outp[(size_t)(b0 + ln)*Ttot + (t-1)] = osum;
        }
        float xn = (t + 2 < Tin) ? inp[(size_t)(b0 + nn)*Tin + t + 2] : 0.f;

        // ---- one LDS read session: h1(t) slabs 0,1 + h2(t-1) slabs 2,3 ----
        const uint16_t* rb = &Bh[cur][nn*BST + quad*8];
        short8 s0 = *(const short8*)(rb),      s1 = *(const short8*)(rb + 32);
        short8 s2 = *(const short8*)(rb + 64), s3 = *(const short8*)(rb + 96);

        // ================= L2(t): GEMM + cells + wsum =================
        {
            float h2v[2] = {0.f, 0.f};
#pragma unroll
            for (int tl = 0; tl < 2; ++tl) {
                if (!tvt[tl]) continue;
                f32x4 aA = bias2[tl], aB = {0.f,0.f,0.f,0.f};
                aA = MFMA(a2hi[tl][0], s0, aA, 0,0,0);
                aB = MFMA(a2hi[tl][1], s1, aB, 0,0,0);
                aA = MFMA(a2lo[tl][0], s0, aA, 0,0,0);
                aB = MFMA(a2lo[tl][1], s1, aB, 0,0,0);
                aA = MFMA(a2hi[tl][2], s2, aA, 0,0,0);
                aB = MFMA(a2hi[tl][3], s3, aB, 0,0,0);
                aA = MFMA(a2lo[tl][2], s2, aA, 0,0,0);
                aB = MFMA(a2lo[tl][3], s3, aB, 0,0,0);
                float vi = aA[0]+aB[0], vf = aA[1]+aB[1];
                float vg = aA[2]+aB[2], vo = aA[3]+aB[3];
                c2[tl] = __builtin_fmaf(sig2(vf), c2[tl], sig2(vi)*tanh2(vg));
                h2v[tl] = sig2(vo) * tanh2(c2[tl]*TL2E);
                if (uvt[tl]) Bh[nxt][nn*BST + 64 + ut[tl]] = f2bf(h2v[tl]);
            }
            float part = __builtin_fmaf(wlu[0], h2v[0], wlu[1]*h2v[1]);
            part += __shfl_xor(part, 16, 64);
            part += __shfl_xor(part, 32, 64);
            if (quad == 0) wsum[cur][wv*17 + nn] = part;
        }

        // ========= L1(t+1) fused (input mode: x already in register) =========
        if (inmode) {
#pragma unroll
            for (int tl = 0; tl < 2; ++tl) {
                if (!tvt[tl]) continue;
                f32x4 aA, aB = {0.f,0.f,0.f,0.f};
#pragma unroll
                for (int i = 0; i < 4; ++i)
                    aA[i] = __builtin_fmaf(wih1v[tl][i], xreg, bias1[tl][i]);
                aA = MFMA(a1hi[tl][0], s0, aA, 0,0,0);
                aB = MFMA(a1hi[tl][1], s1, aB, 0,0,0);
                aA = MFMA(a1lo[tl][0], s0, aA, 0,0,0);
                aB = MFMA(a1lo[tl][1], s1, aB, 0,0,0);
                float vi = aA[0]+aB[0], vf = aA[1]+aB[1];
                float vg = aA[2]+aB[2], vo = aA[3]+aB[3];
                c1[tl] = __builtin_fmaf(sig2(vf), c1[tl], sig2(vi)*tanh2(vg));
                float h1n = sig2(vo) * tanh2(c1[tl]*TL2E);
                if (uvt[tl]) Bh[nxt][nn*BST + ut[tl]] = f2bf(h1n);
            }
        }
        __syncthreads();                                   // bar 1

        // ===== future sub-phase: x(t+1) = out(t), then L1(t+1) =====
        if (!inmode && t + 1 < Ttot) {
            float osum = blv;
#pragma unroll
            for (int w = 0; w < NW; ++w) osum += wsum[cur][w*17 + nn];
#pragma unroll
            for (int tl = 0; tl < 2; ++tl) {
                if (!tvt[tl]) continue;
                f32x4 aA, aB = {0.f,0.f,0.f,0.f};
#pragma unroll
                for (int i = 0; i < 4; ++i)
                    aA[i] = __builtin_fmaf(wih1v[tl][i], osum, bias1[tl][i]);
                aA = MFMA(a1hi[tl][0], s0, aA, 0,0,0);   // s0,s1 still live
                aB = MFMA(a1hi[tl][1], s1, aB, 0,0,0);
                aA = MFMA(a1lo[tl][0], s0, aA, 0,0,0);
                aB = MFMA(a1lo[tl][1], s1, aB, 0,0,0);
                float vi = aA[0]+aB[0], vf = aA[1]+aB[1];
                float vg = aA[2]+aB[2], vo = aA[3]+aB[3];
                c1[tl] = __builtin_fmaf(sig2(vf), c1[tl], sig2(vi)*tanh2(vg));
                float h1n = sig2(vo) * tanh2(c1[tl]*TL2E);
                if (uvt[tl]) Bh[nxt][nn*BST + ut[tl]] = f2bf(h1n);
            }
            __syncthreads();                               // bar 2 (future only)
        }
        xreg = xn;
    }

    // final output (t = Ttot-1): wsum[(Ttot-1)&1] visible after last barrier
    if (wv == NW-1) {
        float osum = blv;
#pragma unroll
        for (int w = 0; w < NW; ++w) osum += wsum[(Ttot-1)&1][w*17 + nn];
        if (ln < NBB) outp[(size_t)(b0 + ln)*Ttot + (Ttot-1)] = osum;
    }
}

extern "C" void kernel_launch(void* const* d_in, const int* in_sizes, int n_in,
                              void* d_out, int out_size, void* d_ws, size_t ws_size,
                              hipStream_t stream) {
    (void)in_sizes; (void)n_in; (void)out_size; (void)d_ws; (void)ws_size;
    lstm_mfma8<<<dim3(Bsz / NBB), dim3(BLK), 0, stream>>>(
        (const float*)d_in[0], (const float*)d_in[1],
        (const float*)d_in[2], (const float*)d_in[3],
        (const float*)d_in[4], (const float*)d_in[5],
        (const float*)d_in[6], (const float*)d_in[7],
        (const float*)d_in[8], (const float*)d_in[9],
        (const float*)d_in[10], (float*)d_out);
}